// Round 3
// baseline (929.473 us; speedup 1.0000x reference)
//
#include <hip/hip_runtime.h>
#include <math.h>

// B=4, S=4096 -> 16384 tokens; H=4096; E=64; TOP_K=2
#define TOKENS 16384
#define HDIM 4096
#define NE 64

#define BM 256                  // tokens per block
#define BK 16                   // k per LDS chunk
#define KSPLIT 16               // K slices
#define KSLICE (HDIM / KSPLIT)  // 256
#define LDA 260                 // As row stride (k-major), mult of 4 for b128 align
#define LDW 68                  // Ws row stride

// GEMM: P[ks][tok][e] = sum_{k in slice} A[tok,k] * W[e,k]
// 256 thr (4 waves), 8x8 micro-tile (64 acc) -> 1 B/MAC LDS read traffic:
// per wave-k: 64 FMA (128 VALU cyc) vs 4 ds_read_b128 (8-lane broadcast,
// 2 addrs/bank = free). 1024 blocks -> 4 blocks/CU, 4 waves/SIMD.
__global__ __launch_bounds__(256, 4) void router_gemm(const float* __restrict__ A,
                                                      const float* __restrict__ W,
                                                      float* __restrict__ P) {
  __shared__ float As[BK * LDA];  // [k][token]
  __shared__ float Ws[BK * LDW];  // [k][expert]

  const int tid = threadIdx.x;
  const int bt = blockIdx.x;  // token tile (256 tokens)
  const int ks = blockIdx.y;  // K slice

  // staging map: groups of 4 lanes cover 16 k of one token (64B segments)
  const int stok = tid >> 2;       // 0..63 (+64*i for i=0..3)
  const int sk = (tid & 3) * 4;    // k offset 0,4,8,12
  const float* Ab = A + (size_t)(bt * BM + stok) * HDIM + (size_t)ks * KSLICE + sk;
  const float* Wb = W + (size_t)stok * HDIM + (size_t)ks * KSLICE + sk;  // stok==expert

  // compute map
  const int tx = tid & 7;   // expert group: experts tx*8..+7
  const int ty = tid >> 3;  // token group: tokens ty*8..+7

  float acc[8][8];
#pragma unroll
  for (int i = 0; i < 8; ++i)
#pragma unroll
    for (int j = 0; j < 8; ++j) acc[i][j] = 0.f;

  // prefetch chunk 0 into registers
  float4 pa[4], pw;
#pragma unroll
  for (int i = 0; i < 4; ++i) pa[i] = *(const float4*)(Ab + (size_t)i * 64 * HDIM);
  pw = *(const float4*)(Wb);

  for (int kc = 0; kc < KSLICE; kc += BK) {
    // stage regs -> LDS (k-major transpose). Scalar writes: 2 lanes/bank = free.
#pragma unroll
    for (int i = 0; i < 4; ++i) {
      const int col = stok + i * 64;
      As[(sk + 0) * LDA + col] = pa[i].x;
      As[(sk + 1) * LDA + col] = pa[i].y;
      As[(sk + 2) * LDA + col] = pa[i].z;
      As[(sk + 3) * LDA + col] = pa[i].w;
    }
    Ws[(sk + 0) * LDW + stok] = pw.x;
    Ws[(sk + 1) * LDW + stok] = pw.y;
    Ws[(sk + 2) * LDW + stok] = pw.z;
    Ws[(sk + 3) * LDW + stok] = pw.w;
    __syncthreads();

    // prefetch next chunk (overlaps compute)
    if (kc + BK < KSLICE) {
#pragma unroll
      for (int i = 0; i < 4; ++i)
        pa[i] = *(const float4*)(Ab + (size_t)i * 64 * HDIM + kc + BK);
      pw = *(const float4*)(Wb + kc + BK);
    }

#pragma unroll
    for (int k = 0; k < BK; ++k) {
      float a[8], w[8];
      *(float4*)&a[0] = *(const float4*)&As[k * LDA + ty * 8];
      *(float4*)&a[4] = *(const float4*)&As[k * LDA + ty * 8 + 4];
      *(float4*)&w[0] = *(const float4*)&Ws[k * LDW + tx * 8];
      *(float4*)&w[4] = *(const float4*)&Ws[k * LDW + tx * 8 + 4];
#pragma unroll
      for (int i = 0; i < 8; ++i)
#pragma unroll
        for (int j = 0; j < 8; ++j) acc[i][j] = fmaf(a[i], w[j], acc[i][j]);
    }
    __syncthreads();
  }

  // write partials P[ks][tok][e]; per wave row: 8 experts x 8 lanes-of-tx
  // -> 256B contiguous segments per token row
  float* Pb = P + ((size_t)ks * TOKENS + (size_t)bt * BM + ty * 8) * NE + tx * 8;
#pragma unroll
  for (int i = 0; i < 8; ++i) {
    *(float4*)(Pb + (size_t)i * NE) =
        make_float4(acc[i][0], acc[i][1], acc[i][2], acc[i][3]);
    *(float4*)(Pb + (size_t)i * NE + 4) =
        make_float4(acc[i][4], acc[i][5], acc[i][6], acc[i][7]);
  }
}

// Finalize: wave = token, lane = expert. Coalesced partial-sum reads,
// shuffle softmax + top-2 (ballot lowest-index tie-break == np/jax).
__global__ __launch_bounds__(256) void router_finalize(const float* __restrict__ P,
                                                       float* __restrict__ out) {
  const int lane = threadIdx.x & 63;
  const int wave = threadIdx.x >> 6;
  const int tok = blockIdx.x * 4 + wave;

  float l = 0.f;
#pragma unroll
  for (int s = 0; s < KSPLIT; ++s)
    l += P[((size_t)s * TOKENS + tok) * NE + lane];

  float m = l;
#pragma unroll
  for (int off = 32; off >= 1; off >>= 1) m = fmaxf(m, __shfl_xor(m, off, 64));

  const float e = expf(l - m);
  float sum = e;
#pragma unroll
  for (int off = 32; off >= 1; off >>= 1) sum += __shfl_xor(sum, off, 64);

  const float p = e / sum;
  out[(size_t)tok * NE + lane] = p;

  float m0 = p;
#pragma unroll
  for (int off = 32; off >= 1; off >>= 1) m0 = fmaxf(m0, __shfl_xor(m0, off, 64));
  const unsigned long long b0 = __ballot(p == m0);
  const int i0 = __ffsll(b0) - 1;

  const float pm = (lane == i0) ? -1.f : p;
  float m1 = pm;
#pragma unroll
  for (int off = 32; off >= 1; off >>= 1) m1 = fmaxf(m1, __shfl_xor(m1, off, 64));
  const unsigned long long b1 = __ballot(pm == m1);
  const int i1 = __ffsll(b1) - 1;

  if (lane == 0) {
    float* idxo = out + (size_t)TOKENS * NE + (size_t)tok * 2;
    idxo[0] = (float)i0;
    idxo[1] = (float)i1;
    float* wo = out + (size_t)TOKENS * NE + (size_t)TOKENS * 2 + (size_t)tok * 2;
    const float d = m0 + m1;
    wo[0] = m0 / d;
    wo[1] = m1 / d;
  }
}

extern "C" void kernel_launch(void* const* d_in, const int* in_sizes, int n_in,
                              void* d_out, int out_size, void* d_ws, size_t ws_size,
                              hipStream_t stream) {
  const float* A = (const float*)d_in[0];  // hidden_states [16384, 4096] f32
  const float* W = (const float*)d_in[1];  // gate_weight   [64, 4096] f32
  float* out = (float*)d_out;
  float* P = (float*)d_ws;                 // 16*16384*64*4 = 64 MiB partials

  dim3 gridA(TOKENS / BM, KSPLIT);         // 64 x 16 = 1024 blocks, 256 thr
  router_gemm<<<gridA, 256, 0, stream>>>(A, W, P);
  router_finalize<<<TOKENS / 4, 256, 0, stream>>>(P, out);
}

// Round 4
// 404.719 us; speedup vs baseline: 2.2966x; 2.2966x over previous
//
#include <hip/hip_runtime.h>
#include <math.h>

// B=4, S=4096 -> 16384 tokens; H=4096; E=64; TOP_K=2
#define TOKENS 16384
#define HDIM 4096
#define NE 64

#define BM 256                  // tokens per block
#define BK 16                   // k per LDS chunk
#define KSPLIT 16               // K slices
#define KSLICE (HDIM / KSPLIT)  // 256
#define LDA 260                 // As row stride (k-major), mult of 4 for b128 align
#define LDW 68                  // Ws row stride

// GEMM: P[ks][tok][e] = sum_{k in slice} A[tok,k] * W[e,k]
// 256 thr (4 waves), 8x8 micro-tile (64 acc VGPRs).
// NOTE: no min-waves in launch_bounds! Round 3's (256,4) capped the
// allocator at 64 VGPRs -> ~100 regs spilled -> 1.6 GB scratch writes,
// VALUBusy 9.6%, 672 us. Compiler needs ~160 VGPRs here (3 waves/SIMD).
__global__ __launch_bounds__(256) void router_gemm(const float* __restrict__ A,
                                                   const float* __restrict__ W,
                                                   float* __restrict__ P) {
  __shared__ float As[BK * LDA];  // [k][token]
  __shared__ float Ws[BK * LDW];  // [k][expert]

  const int tid = threadIdx.x;
  const int bt = blockIdx.x;  // token tile (256 tokens)
  const int ks = blockIdx.y;  // K slice

  // staging map: quad of lanes covers 16 k (64B) of one token row; the
  // other 64B half-line of each 128B line arrives next chunk -> L2 hit.
  const int stok = tid >> 2;     // 0..63 (+64*i)
  const int sk = (tid & 3) * 4;  // k offset 0,4,8,12
  const float* Ab = A + (size_t)(bt * BM + stok) * HDIM + (size_t)ks * KSLICE + sk;
  const float* Wb = W + (size_t)stok * HDIM + (size_t)ks * KSLICE + sk;  // stok==expert

  // compute map
  const int tx = tid & 7;   // expert group: experts tx*8..+7
  const int ty = tid >> 3;  // token group: tokens ty*8..+7

  float acc[8][8];
#pragma unroll
  for (int i = 0; i < 8; ++i)
#pragma unroll
    for (int j = 0; j < 8; ++j) acc[i][j] = 0.f;

  // prefetch chunk 0 into registers
  float4 pa[4], pw;
#pragma unroll
  for (int i = 0; i < 4; ++i) pa[i] = *(const float4*)(Ab + (size_t)i * 64 * HDIM);
  pw = *(const float4*)(Wb);

  for (int kc = 0; kc < KSLICE; kc += BK) {
    // stage regs -> LDS (k-major transpose). Scalar writes: 2 lanes/bank = free.
#pragma unroll
    for (int i = 0; i < 4; ++i) {
      const int col = stok + i * 64;
      As[(sk + 0) * LDA + col] = pa[i].x;
      As[(sk + 1) * LDA + col] = pa[i].y;
      As[(sk + 2) * LDA + col] = pa[i].z;
      As[(sk + 3) * LDA + col] = pa[i].w;
    }
    Ws[(sk + 0) * LDW + stok] = pw.x;
    Ws[(sk + 1) * LDW + stok] = pw.y;
    Ws[(sk + 2) * LDW + stok] = pw.z;
    Ws[(sk + 3) * LDW + stok] = pw.w;
    __syncthreads();

    // prefetch next chunk (overlaps compute)
    if (kc + BK < KSLICE) {
#pragma unroll
      for (int i = 0; i < 4; ++i)
        pa[i] = *(const float4*)(Ab + (size_t)i * 64 * HDIM + kc + BK);
      pw = *(const float4*)(Wb + kc + BK);
    }

#pragma unroll
    for (int k = 0; k < BK; ++k) {
      float a[8], w[8];
      *(float4*)&a[0] = *(const float4*)&As[k * LDA + ty * 8];
      *(float4*)&a[4] = *(const float4*)&As[k * LDA + ty * 8 + 4];
      *(float4*)&w[0] = *(const float4*)&Ws[k * LDW + tx * 8];
      *(float4*)&w[4] = *(const float4*)&Ws[k * LDW + tx * 8 + 4];
#pragma unroll
      for (int i = 0; i < 8; ++i)
#pragma unroll
        for (int j = 0; j < 8; ++j) acc[i][j] = fmaf(a[i], w[j], acc[i][j]);
    }
    __syncthreads();
  }

  // write partials P[ks][tok][e]
  float* Pb = P + ((size_t)ks * TOKENS + (size_t)bt * BM + ty * 8) * NE + tx * 8;
#pragma unroll
  for (int i = 0; i < 8; ++i) {
    *(float4*)(Pb + (size_t)i * NE) =
        make_float4(acc[i][0], acc[i][1], acc[i][2], acc[i][3]);
    *(float4*)(Pb + (size_t)i * NE + 4) =
        make_float4(acc[i][4], acc[i][5], acc[i][6], acc[i][7]);
  }
}

// Finalize: wave = token, lane = expert. Coalesced partial-sum reads,
// shuffle softmax + top-2 (ballot lowest-index tie-break == np/jax).
__global__ __launch_bounds__(256) void router_finalize(const float* __restrict__ P,
                                                       float* __restrict__ out) {
  const int lane = threadIdx.x & 63;
  const int wave = threadIdx.x >> 6;
  const int tok = blockIdx.x * 4 + wave;

  float l = 0.f;
#pragma unroll
  for (int s = 0; s < KSPLIT; ++s)
    l += P[((size_t)s * TOKENS + tok) * NE + lane];

  float m = l;
#pragma unroll
  for (int off = 32; off >= 1; off >>= 1) m = fmaxf(m, __shfl_xor(m, off, 64));

  const float e = expf(l - m);
  float sum = e;
#pragma unroll
  for (int off = 32; off >= 1; off >>= 1) sum += __shfl_xor(sum, off, 64);

  const float p = e / sum;
  out[(size_t)tok * NE + lane] = p;

  float m0 = p;
#pragma unroll
  for (int off = 32; off >= 1; off >>= 1) m0 = fmaxf(m0, __shfl_xor(m0, off, 64));
  const unsigned long long b0 = __ballot(p == m0);
  const int i0 = __ffsll(b0) - 1;

  const float pm = (lane == i0) ? -1.f : p;
  float m1 = pm;
#pragma unroll
  for (int off = 32; off >= 1; off >>= 1) m1 = fmaxf(m1, __shfl_xor(m1, off, 64));
  const unsigned long long b1 = __ballot(pm == m1);
  const int i1 = __ffsll(b1) - 1;

  if (lane == 0) {
    float* idxo = out + (size_t)TOKENS * NE + (size_t)tok * 2;
    idxo[0] = (float)i0;
    idxo[1] = (float)i1;
    float* wo = out + (size_t)TOKENS * NE + (size_t)TOKENS * 2 + (size_t)tok * 2;
    const float d = m0 + m1;
    wo[0] = m0 / d;
    wo[1] = m1 / d;
  }
}

extern "C" void kernel_launch(void* const* d_in, const int* in_sizes, int n_in,
                              void* d_out, int out_size, void* d_ws, size_t ws_size,
                              hipStream_t stream) {
  const float* A = (const float*)d_in[0];  // hidden_states [16384, 4096] f32
  const float* W = (const float*)d_in[1];  // gate_weight   [64, 4096] f32
  float* out = (float*)d_out;
  float* P = (float*)d_ws;                 // 16*16384*64*4 = 64 MiB partials

  dim3 gridA(TOKENS / BM, KSPLIT);         // 64 x 16 = 1024 blocks, 256 thr
  router_gemm<<<gridA, 256, 0, stream>>>(A, W, P);
  router_finalize<<<TOKENS / 4, 256, 0, stream>>>(P, out);
}